// Round 1
// baseline (1025.717 us; speedup 1.0000x reference)
//
#include <hip/hip_runtime.h>

#define N_NODESC 100000
#define N_EDGESC 1600000
#define DIM 128

typedef __bf16 bf16x8 __attribute__((ext_vector_type(8)));
typedef float f32x4 __attribute__((ext_vector_type(4)));

__device__ __forceinline__ float asf(unsigned u) { return __uint_as_float(u); }
__device__ __forceinline__ unsigned short f2bf(float f) {
    unsigned u = __float_as_uint(f);
    u += 0x7fffu + ((u >> 16) & 1u);
    return (unsigned short)(u >> 16);
}

// ---------------- weight convert: 7 matrices fp32 [k][c] -> bf16 transposed [c][k]
__global__ __launch_bounds__(256) void k_wcvt(const float* __restrict__ w0, const float* __restrict__ w1,
                                              const float* __restrict__ w2, const float* __restrict__ w3,
                                              const float* __restrict__ w4, const float* __restrict__ w5,
                                              const float* __restrict__ w6, unsigned short* __restrict__ wt) {
    int gid = blockIdx.x * 256 + threadIdx.x;   // 0..114687
    int m = gid >> 14;
    int r = gid & 16383;
    int c = r >> 7;
    int k = r & 127;
    const float* src;
    switch (m) {
        case 0: src = w0; break; case 1: src = w1; break; case 2: src = w2; break;
        case 3: src = w3; break; case 4: src = w4; break; case 5: src = w5; break;
        default: src = w6; break;
    }
    wt[gid] = f2bf(src[k * 128 + c]);
}

// ---------------- x fp32 -> bf16
__global__ __launch_bounds__(256) void k_xcvt(const float* __restrict__ x, unsigned short* __restrict__ xbf) {
    size_t base = ((size_t)blockIdx.x * 256 + threadIdx.x) * 4;
    float4 v = *(const float4*)(x + base);
    unsigned lo = (unsigned)f2bf(v.x) | ((unsigned)f2bf(v.y) << 16);
    unsigned hi = (unsigned)f2bf(v.z) | ((unsigned)f2bf(v.w) << 16);
    *(uint2*)(xbf + base) = make_uint2(lo, hi);
}

// ---------------- CSR build
__global__ __launch_bounds__(256) void k_hist(const int* __restrict__ ei, int* __restrict__ counts) {
    int e = blockIdx.x * 256 + threadIdx.x;
    if (e < N_EDGESC) atomicAdd(&counts[ei[N_EDGESC + e]], 1);
}

__global__ __launch_bounds__(1024) void k_scan(const int* __restrict__ counts, int* __restrict__ offs,
                                               int* __restrict__ cursor, int n) {
    __shared__ int wsum[16];
    __shared__ int carry_sh;
    int tid = threadIdx.x;
    int lane = tid & 63;
    int wid = tid >> 6;
    if (tid == 0) carry_sh = 0;
    __syncthreads();
    for (int base = 0; base < n; base += 1024) {
        int i = base + tid;
        int orig = (i < n) ? counts[i] : 0;
        int v = orig;
        #pragma unroll
        for (int d = 1; d < 64; d <<= 1) {
            int t = __shfl_up(v, d, 64);
            if (lane >= d) v += t;
        }
        if (lane == 63) wsum[wid] = v;
        __syncthreads();
        if (tid == 0) {
            int s = 0;
            #pragma unroll
            for (int k = 0; k < 16; k++) { int t = wsum[k]; wsum[k] = s; s += t; }
        }
        __syncthreads();
        int carry = carry_sh;
        int excl = carry + wsum[wid] + (v - orig);
        if (i < n) { offs[i] = excl; cursor[i] = excl; }
        __syncthreads();
        if (tid == 1023) carry_sh = carry + wsum[15] + v;
        __syncthreads();
    }
    if (tid == 0) offs[n] = carry_sh;
}

__global__ __launch_bounds__(256) void k_scatter(const int* __restrict__ ei, const float* __restrict__ ew,
                                                 int* __restrict__ cursor, int* __restrict__ esrc,
                                                 float* __restrict__ ews) {
    int e = blockIdx.x * 256 + threadIdx.x;
    if (e >= N_EDGESC) return;
    int c = ei[N_EDGESC + e];
    int p = atomicAdd(&cursor[c], 1);
    esrc[p] = ei[e];
    ews[p] = ew[e];
}

// ---------------- aggregation: one wave per node, weighted mean of h_bf[src]
__global__ __launch_bounds__(256) void k_agg(const unsigned short* __restrict__ hbf, const int* __restrict__ offs,
                                             const int* __restrict__ esrc, const float* __restrict__ ews,
                                             unsigned short* __restrict__ xnbf) {
    int wid = threadIdx.x >> 6;
    int lane = threadIdx.x & 63;
    int n = blockIdx.x * 4 + wid;
    int s = offs[n], e = offs[n + 1];
    float a0 = 0.f, a1 = 0.f, wsum = 0.f;
    int j = s;
    for (; j + 1 < e; j += 2) {
        int s0 = esrc[j], s1 = esrc[j + 1];
        float w0 = ews[j], w1 = ews[j + 1];
        unsigned v0 = *(const unsigned*)(hbf + (size_t)s0 * 128 + lane * 2);
        unsigned v1 = *(const unsigned*)(hbf + (size_t)s1 * 128 + lane * 2);
        a0 += w0 * asf(v0 << 16); a1 += w0 * asf(v0 & 0xffff0000u);
        a0 += w1 * asf(v1 << 16); a1 += w1 * asf(v1 & 0xffff0000u);
        wsum += w0 + w1;
    }
    if (j < e) {
        int s0 = esrc[j]; float w0 = ews[j];
        unsigned v0 = *(const unsigned*)(hbf + (size_t)s0 * 128 + lane * 2);
        a0 += w0 * asf(v0 << 16); a1 += w0 * asf(v0 & 0xffff0000u);
        wsum += w0;
    }
    float inv = 1.f / fmaxf(wsum, 1.f);
    unsigned out = (unsigned)f2bf(a0 * inv) | ((unsigned)f2bf(a1 * inv) << 16);
    *(unsigned*)(xnbf + (size_t)n * 128 + lane * 2) = out;
}

// ---------------- input GEMM: h = relu(x @ W_in + b), writes fp32 + bf16
__global__ __launch_bounds__(256) void k_gemm_in(const unsigned short* __restrict__ Abf,
                                                 const unsigned short* __restrict__ WT,
                                                 const float* __restrict__ bias,
                                                 float* __restrict__ Hout, unsigned short* __restrict__ Hbf, int M) {
    int tid = threadIdx.x;
    int lane = tid & 63;
    int wid = tid >> 6;
    int l15 = lane & 15;
    int quad = lane >> 4;
    int rowbase0 = blockIdx.x * 128 + wid * 32;
    f32x4 acc[2][8] = {};
    for (int kt = 0; kt < 4; ++kt) {
        int k0 = kt * 32 + quad * 8;
        bf16x8 a[2];
        #pragma unroll
        for (int rs = 0; rs < 2; ++rs) {
            int r = rowbase0 + rs * 16 + l15;
            r = min(r, M - 1);
            a[rs] = *(const bf16x8*)(Abf + (size_t)r * 128 + k0);
        }
        #pragma unroll
        for (int nt = 0; nt < 8; ++nt) {
            int c = nt * 16 + l15;
            bf16x8 b = *(const bf16x8*)(WT + c * 128 + k0);
            #pragma unroll
            for (int rs = 0; rs < 2; ++rs)
                acc[rs][nt] = __builtin_amdgcn_mfma_f32_16x16x32_bf16(a[rs], b, acc[rs][nt], 0, 0, 0);
        }
    }
    #pragma unroll
    for (int nt = 0; nt < 8; ++nt) {
        int c = nt * 16 + l15;
        float bv = bias[c];
        #pragma unroll
        for (int rs = 0; rs < 2; ++rs) {
            int rb = rowbase0 + rs * 16 + quad * 4;
            #pragma unroll
            for (int i = 0; i < 4; ++i) {
                int r = rb + i;
                float v = fmaxf(acc[rs][nt][i] + bv, 0.f);
                if (r < M) {
                    Hout[(size_t)r * 128 + c] = v;
                    Hbf[(size_t)r * 128 + c] = f2bf(v);
                }
            }
        }
    }
}

// ---------------- layer GEMM: t = h@Ws + xn@Wn + (bs+bn), + column stats for BN
__global__ __launch_bounds__(256) void k_gemm_layer(const unsigned short* __restrict__ Abf,
                                                    const unsigned short* __restrict__ Xbf,
                                                    const unsigned short* __restrict__ WsT,
                                                    const unsigned short* __restrict__ WnT,
                                                    const float* __restrict__ bs, const float* __restrict__ bn,
                                                    float* __restrict__ Tout,
                                                    float* __restrict__ colsum, float* __restrict__ colsq, int M) {
    __shared__ float s_sum[128];
    __shared__ float s_sq[128];
    int tid = threadIdx.x;
    if (tid < 128) { s_sum[tid] = 0.f; s_sq[tid] = 0.f; }
    __syncthreads();
    int lane = tid & 63;
    int wid = tid >> 6;
    int l15 = lane & 15;
    int quad = lane >> 4;
    int rowbase0 = blockIdx.x * 128 + wid * 32;
    f32x4 acc[2][8] = {};
    for (int kt = 0; kt < 4; ++kt) {
        int k0 = kt * 32 + quad * 8;
        bf16x8 ah[2], ax[2];
        #pragma unroll
        for (int rs = 0; rs < 2; ++rs) {
            int r = rowbase0 + rs * 16 + l15;
            r = min(r, M - 1);
            ah[rs] = *(const bf16x8*)(Abf + (size_t)r * 128 + k0);
            ax[rs] = *(const bf16x8*)(Xbf + (size_t)r * 128 + k0);
        }
        #pragma unroll
        for (int nt = 0; nt < 8; ++nt) {
            int c = nt * 16 + l15;
            bf16x8 bsv = *(const bf16x8*)(WsT + c * 128 + k0);
            bf16x8 bnv = *(const bf16x8*)(WnT + c * 128 + k0);
            #pragma unroll
            for (int rs = 0; rs < 2; ++rs) {
                acc[rs][nt] = __builtin_amdgcn_mfma_f32_16x16x32_bf16(ah[rs], bsv, acc[rs][nt], 0, 0, 0);
                acc[rs][nt] = __builtin_amdgcn_mfma_f32_16x16x32_bf16(ax[rs], bnv, acc[rs][nt], 0, 0, 0);
            }
        }
    }
    #pragma unroll
    for (int nt = 0; nt < 8; ++nt) {
        int c = nt * 16 + l15;
        float bv = bs[c] + bn[c];
        float ps = 0.f, pq = 0.f;
        #pragma unroll
        for (int rs = 0; rs < 2; ++rs) {
            int rb = rowbase0 + rs * 16 + quad * 4;
            #pragma unroll
            for (int i = 0; i < 4; ++i) {
                int r = rb + i;
                float v = acc[rs][nt][i] + bv;
                if (r < M) {
                    Tout[(size_t)r * 128 + c] = v;
                    ps += v; pq += v * v;
                }
            }
        }
        ps += __shfl_xor(ps, 16); pq += __shfl_xor(pq, 16);
        ps += __shfl_xor(ps, 32); pq += __shfl_xor(pq, 32);
        if (quad == 0) { atomicAdd(&s_sum[c], ps); atomicAdd(&s_sq[c], pq); }
    }
    __syncthreads();
    if (tid < 128) atomicAdd(&colsum[tid], s_sum[tid]);
    else atomicAdd(&colsq[tid - 128], s_sq[tid - 128]);
}

// ---------------- BN apply + residual (+relu, + bf16 copy for next layer)
template <int RELU, int FINAL>
__global__ __launch_bounds__(256) void k_bn(const float* __restrict__ Tin, const float* __restrict__ colsum,
                                            const float* __restrict__ colsq, const float* __restrict__ gma,
                                            const float* __restrict__ bta, float* __restrict__ H,
                                            unsigned short* __restrict__ Hbf, float* __restrict__ Out) {
    size_t base = ((size_t)blockIdx.x * 256 + threadIdx.x) * 4;
    int c0 = (int)(base & 127);
    float4 t = *(const float4*)(Tin + base);
    float4 s = *(const float4*)(colsum + c0);
    float4 q = *(const float4*)(colsq + c0);
    float4 gv = *(const float4*)(gma + c0);
    float4 bv = *(const float4*)(bta + c0);
    float4 h = *(const float4*)(H + base);
    const float invM = 1.0f / (float)N_NODESC;
    float tt[4] = {t.x, t.y, t.z, t.w};
    float ss[4] = {s.x, s.y, s.z, s.w};
    float qq[4] = {q.x, q.y, q.z, q.w};
    float gg[4] = {gv.x, gv.y, gv.z, gv.w};
    float bb[4] = {bv.x, bv.y, bv.z, bv.w};
    float hh[4] = {h.x, h.y, h.z, h.w};
    float r[4];
    #pragma unroll
    for (int j = 0; j < 4; ++j) {
        float mu = ss[j] * invM;
        float var = qq[j] * invM - mu * mu;
        float is = rsqrtf(var + 1e-5f);
        float v = (tt[j] - mu) * is * gg[j] + bb[j];
        if (RELU) v = fmaxf(v, 0.f);
        r[j] = hh[j] + v;
    }
    if (FINAL) {
        *(float4*)(Out + base) = make_float4(r[0], r[1], r[2], r[3]);
    } else {
        *(float4*)(H + base) = make_float4(r[0], r[1], r[2], r[3]);
        unsigned lo = (unsigned)f2bf(r[0]) | ((unsigned)f2bf(r[1]) << 16);
        unsigned hi = (unsigned)f2bf(r[2]) | ((unsigned)f2bf(r[3]) << 16);
        *(uint2*)(Hbf + base) = make_uint2(lo, hi);
    }
}

// ---------------- host
static inline size_t al256(size_t x) { return (x + 255) & ~(size_t)255; }

extern "C" void kernel_launch(void* const* d_in, const int* in_sizes, int n_in,
                              void* d_out, int out_size, void* d_ws, size_t ws_size,
                              hipStream_t stream) {
    const float* x    = (const float*)d_in[0];
    const int*   ei   = (const int*)d_in[1];
    const float* ew   = (const float*)d_in[2];
    const float* W_in = (const float*)d_in[3];
    const float* b_in = (const float*)d_in[4];
    const float* Ws[3] = {(const float*)d_in[5],  (const float*)d_in[11], (const float*)d_in[17]};
    const float* bs[3] = {(const float*)d_in[6],  (const float*)d_in[12], (const float*)d_in[18]};
    const float* Wn[3] = {(const float*)d_in[7],  (const float*)d_in[13], (const float*)d_in[19]};
    const float* bn[3] = {(const float*)d_in[8],  (const float*)d_in[14], (const float*)d_in[20]};
    const float* g[3]  = {(const float*)d_in[9],  (const float*)d_in[15], (const float*)d_in[21]};
    const float* be[3] = {(const float*)d_in[10], (const float*)d_in[16], (const float*)d_in[22]};

    char* ws = (char*)d_ws;
    size_t off = 0;
    const size_t nElem = (size_t)N_NODESC * DIM;          // 12.8M
    float*          h      = (float*)(ws + off);          off = al256(off + nElem * 4);
    unsigned short* hbf    = (unsigned short*)(ws + off); off = al256(off + nElem * 2);
    unsigned short* xnbf   = (unsigned short*)(ws + off); off = al256(off + nElem * 2);
    unsigned short* wt     = (unsigned short*)(ws + off); off = al256(off + 7 * 16384 * 2);
    int*            counts = (int*)(ws + off);            off = al256(off + (size_t)N_NODESC * 4);
    int*            offs   = (int*)(ws + off);            off = al256(off + ((size_t)N_NODESC + 1) * 4);
    int*            cursor = (int*)(ws + off);            off = al256(off + ((size_t)N_NODESC + 1) * 4);
    int*            esrc   = (int*)(ws + off);            off = al256(off + (size_t)N_EDGESC * 4);
    float*          ews    = (float*)(ws + off);          off = al256(off + (size_t)N_EDGESC * 4);
    float*          stats  = (float*)(ws + off);          off = al256(off + 3 * 256 * 4);
    unsigned short* xbf    = xnbf;   // alias: x_bf only needed before layer-0 aggregate
    float*          t      = (float*)d_out;               // GEMM output scratch lives in d_out

    hipMemsetAsync(counts, 0, (size_t)N_NODESC * 4, stream);
    hipMemsetAsync(stats, 0, 3 * 256 * 4, stream);

    k_wcvt<<<448, 256, 0, stream>>>(W_in, Ws[0], Wn[0], Ws[1], Wn[1], Ws[2], Wn[2], wt);
    k_xcvt<<<12500, 256, 0, stream>>>(x, xbf);
    k_hist<<<6250, 256, 0, stream>>>(ei, counts);
    k_scan<<<1, 1024, 0, stream>>>(counts, offs, cursor, N_NODESC);
    k_scatter<<<6250, 256, 0, stream>>>(ei, ew, cursor, esrc, ews);

    k_gemm_in<<<782, 256, 0, stream>>>(xbf, wt, b_in, h, hbf, N_NODESC);

    for (int l = 0; l < 3; ++l) {
        k_agg<<<25000, 256, 0, stream>>>(hbf, offs, esrc, ews, xnbf);
        k_gemm_layer<<<782, 256, 0, stream>>>(hbf, xnbf,
                                              wt + (size_t)(1 + 2 * l) * 16384,
                                              wt + (size_t)(2 + 2 * l) * 16384,
                                              bs[l], bn[l], t,
                                              stats + l * 256, stats + l * 256 + 128, N_NODESC);
        if (l < 2)
            k_bn<1, 0><<<12500, 256, 0, stream>>>(t, stats + l * 256, stats + l * 256 + 128,
                                                  g[l], be[l], h, hbf, nullptr);
        else
            k_bn<0, 1><<<12500, 256, 0, stream>>>(t, stats + l * 256, stats + l * 256 + 128,
                                                  g[l], be[l], h, nullptr, (float*)d_out);
    }
}

// Round 4
// 753.842 us; speedup vs baseline: 1.3607x; 1.3607x over previous
//
#include <hip/hip_runtime.h>

#define N_NODESC 100000
#define N_EDGESC 1600000
#define DIM 128
#define SCAN_NB 49   // ceil(100000 / 2048)

typedef __bf16 bf16x8 __attribute__((ext_vector_type(8)));
typedef unsigned short u16x8 __attribute__((ext_vector_type(8)));
typedef float f32x4 __attribute__((ext_vector_type(4)));

__device__ __forceinline__ float asf(unsigned u) { return __uint_as_float(u); }
__device__ __forceinline__ unsigned short f2bf(float f) {
    unsigned u = __float_as_uint(f);
    u += 0x7fffu + ((u >> 16) & 1u);
    return (unsigned short)(u >> 16);
}
__device__ __forceinline__ bf16x8 pack8(const float* f) {
    u16x8 u;
    #pragma unroll
    for (int i = 0; i < 8; ++i) u[i] = f2bf(f[i]);
    return __builtin_bit_cast(bf16x8, u);
}

// ---------------- weight convert: 7 matrices fp32 [k][c] -> bf16 transposed [c][k]
__global__ __launch_bounds__(256) void k_wcvt(const float* __restrict__ w0, const float* __restrict__ w1,
                                              const float* __restrict__ w2, const float* __restrict__ w3,
                                              const float* __restrict__ w4, const float* __restrict__ w5,
                                              const float* __restrict__ w6, unsigned short* __restrict__ wt) {
    int gid = blockIdx.x * 256 + threadIdx.x;   // 0..114687
    int m = gid >> 14;
    int r = gid & 16383;
    int c = r >> 7;
    int k = r & 127;
    const float* src;
    switch (m) {
        case 0: src = w0; break; case 1: src = w1; break; case 2: src = w2; break;
        case 3: src = w3; break; case 4: src = w4; break; case 5: src = w5; break;
        default: src = w6; break;
    }
    wt[gid] = f2bf(src[k * 128 + c]);
}

// ---------------- CSR build
// pass A: histogram + per-edge rank (old count value)
__global__ __launch_bounds__(256) void k_hist(const int* __restrict__ ei, int* __restrict__ counts,
                                              int* __restrict__ rank) {
    int e = blockIdx.x * 256 + threadIdx.x;
    if (e < N_EDGESC) rank[e] = atomicAdd(&counts[ei[N_EDGESC + e]], 1);
}

// phase 1: per-block (2048 counts) sums
__global__ __launch_bounds__(256) void k_scan_bsum(const int* __restrict__ counts, int* __restrict__ bsum) {
    __shared__ int wsh[4];
    int b = blockIdx.x, t = threadIdx.x;
    int i0 = b * 2048 + t * 8;
    int s = 0;
    #pragma unroll
    for (int k = 0; k < 8; ++k) { int i = i0 + k; s += (i < N_NODESC) ? counts[i] : 0; }
    #pragma unroll
    for (int d = 1; d < 64; d <<= 1) s += __shfl_xor(s, d, 64);
    if ((t & 63) == 0) wsh[t >> 6] = s;
    __syncthreads();
    if (t == 0) bsum[b] = wsh[0] + wsh[1] + wsh[2] + wsh[3];
}

// phase 2: single-wave exclusive scan of block sums
__global__ __launch_bounds__(64) void k_scan_boff(const int* __restrict__ bsum, int* __restrict__ boff,
                                                  int* __restrict__ offs) {
    int i = threadIdx.x;
    int v = (i < SCAN_NB) ? bsum[i] : 0;
    int incl = v;
    #pragma unroll
    for (int d = 1; d < 64; d <<= 1) { int t = __shfl_up(incl, d, 64); if (i >= d) incl += t; }
    if (i < SCAN_NB) boff[i] = incl - v;
    if (i == SCAN_NB - 1) offs[N_NODESC] = incl;
}

// phase 3: write exclusive prefixes
__global__ __launch_bounds__(256) void k_scan_write(const int* __restrict__ counts, const int* __restrict__ boff,
                                                    int* __restrict__ offs) {
    __shared__ int woff[4];
    int b = blockIdx.x, t = threadIdx.x;
    int lane = t & 63, wid = t >> 6;
    int i0 = b * 2048 + t * 8;
    int c[8];
    int tsum = 0;
    #pragma unroll
    for (int k = 0; k < 8; ++k) { int i = i0 + k; c[k] = (i < N_NODESC) ? counts[i] : 0; tsum += c[k]; }
    int incl = tsum;
    #pragma unroll
    for (int d = 1; d < 64; d <<= 1) { int tt = __shfl_up(incl, d, 64); if (lane >= d) incl += tt; }
    if (lane == 63) woff[wid] = incl;
    __syncthreads();
    if (t == 0) {
        int s = 0;
        for (int k = 0; k < 4; ++k) { int tt = woff[k]; woff[k] = s; s += tt; }
    }
    __syncthreads();
    int base = boff[b] + woff[wid] + (incl - tsum);
    #pragma unroll
    for (int k = 0; k < 8; ++k) {
        int i = i0 + k;
        if (i < N_NODESC) offs[i] = base;
        base += c[k];
    }
}

// pass B: atomic-free scatter of combined 8B edge records
__global__ __launch_bounds__(256) void k_scatter(const int* __restrict__ ei, const float* __restrict__ ew,
                                                 const int* __restrict__ offs, const int* __restrict__ rank,
                                                 int2* __restrict__ edges) {
    int e = blockIdx.x * 256 + threadIdx.x;
    if (e >= N_EDGESC) return;
    int dst = ei[N_EDGESC + e];
    int p = offs[dst] + rank[e];
    edges[p] = make_int2(ei[e], __float_as_int(ew[e]));
}

// ---------------- aggregation: one wave per node; 16 lanes per row, dwordx4 gathers,
// 4 edges per load instruction, 8 edges in flight per loop body.
__global__ __launch_bounds__(256) void k_agg(const unsigned short* __restrict__ hbf, const int* __restrict__ offs,
                                             const int2* __restrict__ edges, unsigned short* __restrict__ xnbf) {
    int wid = threadIdx.x >> 6;
    int lane = threadIdx.x & 63;
    int g = lane >> 4;          // edge subgroup 0..3
    int q = lane & 15;          // feature sixteenth: elements q*8 .. q*8+7
    int n = blockIdx.x * 4 + wid;
    int s = offs[n], e = offs[n + 1];
    float acc[8] = {};
    float wsum = 0.f;
    for (int j = s; j < e; j += 8) {
        int i0 = j + g, i1 = j + 4 + g;
        bool p0 = i0 < e, p1 = i1 < e;
        int2 r0 = edges[p0 ? i0 : s];
        int2 r1 = edges[p1 ? i1 : s];
        float w0 = p0 ? __int_as_float(r0.y) : 0.f;
        float w1 = p1 ? __int_as_float(r1.y) : 0.f;
        uint4 v0 = *(const uint4*)(hbf + (size_t)r0.x * 128 + q * 8);
        uint4 v1 = *(const uint4*)(hbf + (size_t)r1.x * 128 + q * 8);
        unsigned u0[4] = {v0.x, v0.y, v0.z, v0.w};
        unsigned u1[4] = {v1.x, v1.y, v1.z, v1.w};
        #pragma unroll
        for (int k = 0; k < 4; ++k) {
            acc[2 * k]     += w0 * asf(u0[k] << 16);
            acc[2 * k + 1] += w0 * asf(u0[k] & 0xffff0000u);
            acc[2 * k]     += w1 * asf(u1[k] << 16);
            acc[2 * k + 1] += w1 * asf(u1[k] & 0xffff0000u);
        }
        wsum += w0 + w1;
    }
    #pragma unroll
    for (int k = 0; k < 8; ++k) {
        acc[k] += __shfl_xor(acc[k], 16, 64);
        acc[k] += __shfl_xor(acc[k], 32, 64);
    }
    wsum += __shfl_xor(wsum, 16, 64);
    wsum += __shfl_xor(wsum, 32, 64);
    float inv = 1.f / fmaxf(wsum, 1.f);
    if (lane < 16) {
        unsigned o[4];
        #pragma unroll
        for (int k = 0; k < 4; ++k)
            o[k] = (unsigned)f2bf(acc[2 * k] * inv) | ((unsigned)f2bf(acc[2 * k + 1] * inv) << 16);
        *(uint4*)(xnbf + (size_t)n * 128 + q * 8) = make_uint4(o[0], o[1], o[2], o[3]);
    }
}

// ---------------- input GEMM: h = relu(x @ W_in + b), fp32 A converted in-register
__global__ __launch_bounds__(256) void k_gemm_in(const float* __restrict__ X,
                                                 const unsigned short* __restrict__ WT,
                                                 const float* __restrict__ bias,
                                                 float* __restrict__ Hout, unsigned short* __restrict__ Hbf, int M) {
    int tid = threadIdx.x;
    int lane = tid & 63;
    int wid = tid >> 6;
    int l15 = lane & 15;
    int quad = lane >> 4;
    int rowbase0 = blockIdx.x * 128 + wid * 32;
    f32x4 acc[2][8] = {};
    for (int kt = 0; kt < 4; ++kt) {
        int k0 = kt * 32 + quad * 8;
        bf16x8 a[2];
        #pragma unroll
        for (int rs = 0; rs < 2; ++rs) {
            int r = rowbase0 + rs * 16 + l15;
            r = min(r, M - 1);
            float buf[8];
            *(float4*)buf       = *(const float4*)(X + (size_t)r * 128 + k0);
            *(float4*)(buf + 4) = *(const float4*)(X + (size_t)r * 128 + k0 + 4);
            a[rs] = pack8(buf);
        }
        #pragma unroll
        for (int nt = 0; nt < 8; ++nt) {
            int c = nt * 16 + l15;
            bf16x8 b = *(const bf16x8*)(WT + c * 128 + k0);
            #pragma unroll
            for (int rs = 0; rs < 2; ++rs)
                acc[rs][nt] = __builtin_amdgcn_mfma_f32_16x16x32_bf16(a[rs], b, acc[rs][nt], 0, 0, 0);
        }
    }
    #pragma unroll
    for (int nt = 0; nt < 8; ++nt) {
        int c = nt * 16 + l15;
        float bv = bias[c];
        #pragma unroll
        for (int rs = 0; rs < 2; ++rs) {
            int rb = rowbase0 + rs * 16 + quad * 4;
            #pragma unroll
            for (int i = 0; i < 4; ++i) {
                int r = rb + i;
                float v = fmaxf(acc[rs][nt][i] + bv, 0.f);
                if (r < M) {
                    Hout[(size_t)r * 128 + c] = v;
                    Hbf[(size_t)r * 128 + c] = f2bf(v);
                }
            }
        }
    }
}

// ---------------- layer GEMM: t = h@Ws + xn@Wn + (bs+bn), + column stats for BN
// TBF=1: write t as bf16 (stats computed on dequantized values); TBF=0: fp32.
template <int TBF>
__global__ __launch_bounds__(256) void k_gemm_layer(const unsigned short* __restrict__ Abf,
                                                    const unsigned short* __restrict__ Xbf,
                                                    const unsigned short* __restrict__ WsT,
                                                    const unsigned short* __restrict__ WnT,
                                                    const float* __restrict__ bs, const float* __restrict__ bn,
                                                    float* __restrict__ Tf, unsigned short* __restrict__ Tb,
                                                    float* __restrict__ colsum, float* __restrict__ colsq, int M) {
    __shared__ float s_sum[128];
    __shared__ float s_sq[128];
    int tid = threadIdx.x;
    if (tid < 128) { s_sum[tid] = 0.f; s_sq[tid] = 0.f; }
    __syncthreads();
    int lane = tid & 63;
    int wid = tid >> 6;
    int l15 = lane & 15;
    int quad = lane >> 4;
    int rowbase0 = blockIdx.x * 128 + wid * 32;
    f32x4 acc[2][8] = {};
    for (int kt = 0; kt < 4; ++kt) {
        int k0 = kt * 32 + quad * 8;
        bf16x8 ah[2], ax[2];
        #pragma unroll
        for (int rs = 0; rs < 2; ++rs) {
            int r = rowbase0 + rs * 16 + l15;
            r = min(r, M - 1);
            ah[rs] = *(const bf16x8*)(Abf + (size_t)r * 128 + k0);
            ax[rs] = *(const bf16x8*)(Xbf + (size_t)r * 128 + k0);
        }
        #pragma unroll
        for (int nt = 0; nt < 8; ++nt) {
            int c = nt * 16 + l15;
            bf16x8 bsv = *(const bf16x8*)(WsT + c * 128 + k0);
            bf16x8 bnv = *(const bf16x8*)(WnT + c * 128 + k0);
            #pragma unroll
            for (int rs = 0; rs < 2; ++rs) {
                acc[rs][nt] = __builtin_amdgcn_mfma_f32_16x16x32_bf16(ah[rs], bsv, acc[rs][nt], 0, 0, 0);
                acc[rs][nt] = __builtin_amdgcn_mfma_f32_16x16x32_bf16(ax[rs], bnv, acc[rs][nt], 0, 0, 0);
            }
        }
    }
    #pragma unroll
    for (int nt = 0; nt < 8; ++nt) {
        int c = nt * 16 + l15;
        float bv = bs[c] + bn[c];
        float ps = 0.f, pq = 0.f;
        #pragma unroll
        for (int rs = 0; rs < 2; ++rs) {
            int rb = rowbase0 + rs * 16 + quad * 4;
            #pragma unroll
            for (int i = 0; i < 4; ++i) {
                int r = rb + i;
                float v = acc[rs][nt][i] + bv;
                if (r < M) {
                    if (TBF) {
                        unsigned short qv = f2bf(v);
                        Tb[(size_t)r * 128 + c] = qv;
                        float vq = asf((unsigned)qv << 16);
                        ps += vq; pq += vq * vq;
                    } else {
                        Tf[(size_t)r * 128 + c] = v;
                        ps += v; pq += v * v;
                    }
                }
            }
        }
        ps += __shfl_xor(ps, 16); pq += __shfl_xor(pq, 16);
        ps += __shfl_xor(ps, 32); pq += __shfl_xor(pq, 32);
        if (quad == 0) { atomicAdd(&s_sum[c], ps); atomicAdd(&s_sq[c], pq); }
    }
    __syncthreads();
    if (tid < 128) atomicAdd(&colsum[tid], s_sum[tid]);
    else atomicAdd(&colsq[tid - 128], s_sq[tid - 128]);
}

// ---------------- BN apply + residual (+relu, + bf16 copy for next layer)
template <int RELU, int FINAL, int TBF>
__global__ __launch_bounds__(256) void k_bn(const float* __restrict__ Tf, const unsigned short* __restrict__ Tb,
                                            const float* __restrict__ colsum,
                                            const float* __restrict__ colsq, const float* __restrict__ gma,
                                            const float* __restrict__ bta, float* __restrict__ H,
                                            unsigned short* __restrict__ Hbf, float* __restrict__ Out) {
    size_t base = ((size_t)blockIdx.x * 256 + threadIdx.x) * 4;
    int c0 = (int)(base & 127);
    float tt[4];
    if (TBF) {
        uint2 tv = *(const uint2*)(Tb + base);
        tt[0] = asf(tv.x << 16); tt[1] = asf(tv.x & 0xffff0000u);
        tt[2] = asf(tv.y << 16); tt[3] = asf(tv.y & 0xffff0000u);
    } else {
        float4 t = *(const float4*)(Tf + base);
        tt[0] = t.x; tt[1] = t.y; tt[2] = t.z; tt[3] = t.w;
    }
    float4 s = *(const float4*)(colsum + c0);
    float4 q = *(const float4*)(colsq + c0);
    float4 gv = *(const float4*)(gma + c0);
    float4 bv = *(const float4*)(bta + c0);
    float4 h = *(const float4*)(H + base);
    const float invM = 1.0f / (float)N_NODESC;
    float ss[4] = {s.x, s.y, s.z, s.w};
    float qq[4] = {q.x, q.y, q.z, q.w};
    float gg[4] = {gv.x, gv.y, gv.z, gv.w};
    float bb[4] = {bv.x, bv.y, bv.z, bv.w};
    float hh[4] = {h.x, h.y, h.z, h.w};
    float r[4];
    #pragma unroll
    for (int j = 0; j < 4; ++j) {
        float mu = ss[j] * invM;
        float var = qq[j] * invM - mu * mu;
        float is = rsqrtf(var + 1e-5f);
        float v = (tt[j] - mu) * is * gg[j] + bb[j];
        if (RELU) v = fmaxf(v, 0.f);
        r[j] = hh[j] + v;
    }
    if (FINAL) {
        *(float4*)(Out + base) = make_float4(r[0], r[1], r[2], r[3]);
    } else {
        *(float4*)(H + base) = make_float4(r[0], r[1], r[2], r[3]);
        unsigned lo = (unsigned)f2bf(r[0]) | ((unsigned)f2bf(r[1]) << 16);
        unsigned hi = (unsigned)f2bf(r[2]) | ((unsigned)f2bf(r[3]) << 16);
        *(uint2*)(Hbf + base) = make_uint2(lo, hi);
    }
}

// ---------------- host
static inline size_t al256(size_t x) { return (x + 255) & ~(size_t)255; }

extern "C" void kernel_launch(void* const* d_in, const int* in_sizes, int n_in,
                              void* d_out, int out_size, void* d_ws, size_t ws_size,
                              hipStream_t stream) {
    const float* x    = (const float*)d_in[0];
    const int*   ei   = (const int*)d_in[1];
    const float* ew   = (const float*)d_in[2];
    const float* W_in = (const float*)d_in[3];
    const float* b_in = (const float*)d_in[4];
    const float* Ws[3] = {(const float*)d_in[5],  (const float*)d_in[11], (const float*)d_in[17]};
    const float* bs[3] = {(const float*)d_in[6],  (const float*)d_in[12], (const float*)d_in[18]};
    const float* Wn[3] = {(const float*)d_in[7],  (const float*)d_in[13], (const float*)d_in[19]};
    const float* bn[3] = {(const float*)d_in[8],  (const float*)d_in[14], (const float*)d_in[20]};
    const float* g[3]  = {(const float*)d_in[9],  (const float*)d_in[15], (const float*)d_in[21]};
    const float* be[3] = {(const float*)d_in[10], (const float*)d_in[16], (const float*)d_in[22]};

    char* ws = (char*)d_ws;
    size_t off = 0;
    const size_t nElem = (size_t)N_NODESC * DIM;          // 12.8M
    float*          h      = (float*)(ws + off);          off = al256(off + nElem * 4);
    unsigned short* hbf    = (unsigned short*)(ws + off); off = al256(off + nElem * 2);
    unsigned short* xnbf   = (unsigned short*)(ws + off); off = al256(off + nElem * 2);
    unsigned short* wt     = (unsigned short*)(ws + off); off = al256(off + 7 * 16384 * 2);
    int*            counts = (int*)(ws + off);            off = al256(off + (size_t)N_NODESC * 4);
    int*            offs   = (int*)(ws + off);            off = al256(off + ((size_t)N_NODESC + 1) * 4);
    int*            rank   = (int*)(ws + off);            off = al256(off + (size_t)N_EDGESC * 4);
    int2*           edges  = (int2*)(ws + off);           off = al256(off + (size_t)N_EDGESC * 8);
    int*            bsum_  = (int*)(ws + off);            off = al256(off + SCAN_NB * 4);
    int*            boff_  = (int*)(ws + off);            off = al256(off + SCAN_NB * 4);
    float*          stats  = (float*)(ws + off);          off = al256(off + 3 * 256 * 4);
    // t lives in d_out: bf16 for layers 0/1, fp32 (in-place, element-exact) for layer 2
    unsigned short* t_bf   = (unsigned short*)d_out;
    float*          t_f    = (float*)d_out;

    (void)hipMemsetAsync(counts, 0, (size_t)N_NODESC * 4, stream);
    (void)hipMemsetAsync(stats, 0, 3 * 256 * 4, stream);

    k_wcvt<<<448, 256, 0, stream>>>(W_in, Ws[0], Wn[0], Ws[1], Wn[1], Ws[2], Wn[2], wt);
    k_hist<<<6250, 256, 0, stream>>>(ei, counts, rank);
    k_scan_bsum<<<SCAN_NB, 256, 0, stream>>>(counts, bsum_);
    k_scan_boff<<<1, 64, 0, stream>>>(bsum_, boff_, offs);
    k_scan_write<<<SCAN_NB, 256, 0, stream>>>(counts, boff_, offs);
    k_scatter<<<6250, 256, 0, stream>>>(ei, ew, offs, rank, edges);

    k_gemm_in<<<782, 256, 0, stream>>>(x, wt, b_in, h, hbf, N_NODESC);

    for (int l = 0; l < 3; ++l) {
        k_agg<<<25000, 256, 0, stream>>>(hbf, offs, edges, xnbf);
        if (l < 2) {
            k_gemm_layer<1><<<782, 256, 0, stream>>>(hbf, xnbf,
                                                     wt + (size_t)(1 + 2 * l) * 16384,
                                                     wt + (size_t)(2 + 2 * l) * 16384,
                                                     bs[l], bn[l], nullptr, t_bf,
                                                     stats + l * 256, stats + l * 256 + 128, N_NODESC);
            k_bn<1, 0, 1><<<12500, 256, 0, stream>>>(nullptr, t_bf, stats + l * 256, stats + l * 256 + 128,
                                                     g[l], be[l], h, hbf, nullptr);
        } else {
            k_gemm_layer<0><<<782, 256, 0, stream>>>(hbf, xnbf,
                                                     wt + (size_t)(1 + 2 * l) * 16384,
                                                     wt + (size_t)(2 + 2 * l) * 16384,
                                                     bs[l], bn[l], t_f, nullptr,
                                                     stats + l * 256, stats + l * 256 + 128, N_NODESC);
            k_bn<0, 1, 0><<<12500, 256, 0, stream>>>(t_f, nullptr, stats + l * 256, stats + l * 256 + 128,
                                                     g[l], be[l], h, nullptr, (float*)d_out);
        }
    }
}